// Round 9
// baseline (412.239 us; speedup 1.0000x reference)
//
#include <hip/hip_runtime.h>
#include <hip/hip_bf16.h>
#include <math.h>

// Shapes
#define NN 64
#define CC 64
#define TT 256
#define VV 25
#define DD 64
#define BN_EPS 1e-5f
#define NREP 16

typedef short bf16x8 __attribute__((ext_vector_type(8)));
typedef float f32x4 __attribute__((ext_vector_type(4)));

// ws layout (float offsets)
#define WS_POOLED 0            // [64][64]  (atomic-accumulated means; memset 0)
#define WS_GATE   4096         // [64][4]
#define WS_BFUSE  4352         // [64][64]
#define WS_MASK   8448         // [25][64] f32
#define WS_ABP    10048        // u32[1600] packed bf16 (a=lo16, b=hi16)
#define WS_S1     13248        // [16][1600] replicas (memset 0)
#define WS_S2     38848        // [16][1600]
#define WS_WTB    64448        // ushort[64][64][64] fused W^T bf16
#define WS_YB     195520       // ushort[64][6400][64] y bf16, layout [n][tv][d]

static __device__ __forceinline__ unsigned short f2bf(float x) {
    __hip_bfloat16 h = __float2bfloat16(x);
    return *(unsigned short*)&h;
}
static __device__ __forceinline__ float bf2f(unsigned short u) {
    return __uint_as_float(((unsigned)u) << 16);
}
// async global->LDS, 16B per lane; dest = wave-uniform base + lane*16 (linear)
static __device__ __forceinline__ void gload_lds16(const void* gsrc, void* ldst) {
    typedef const __attribute__((address_space(1))) unsigned int gu32;
    typedef __attribute__((address_space(3))) unsigned int lu32;
    __builtin_amdgcn_global_load_lds((gu32*)gsrc, (lu32*)ldst, 16, 0, 0);
}

// ---------------- K_mask: mask = tanh(FM)+1 ----------------
__global__ __launch_bounds__(256) void k_mask(const float* __restrict__ fmask, float* ws) {
    const int f = blockIdx.x * 256 + threadIdx.x;
    if (f < VV * CC) ws[WS_MASK + f] = tanhf(fmask[f]) + 1.0f;
}

// ---------------- K_xt: x0 -> xT[n][tv][c] bf16 (shift-in + mask, SWIZZLED), + pooling ----------------
// grid (64 tcb, 64 n). Swizzle: 16B granule g within a 128B row stored at g ^ (grow & 7).
__global__ __launch_bounds__(256) void k_xt(const float* __restrict__ x0,
                                            const float* __restrict__ ws,
                                            float* __restrict__ pooled,
                                            unsigned short* __restrict__ xT) {
    __shared__ __align__(16) float tile[64][104];   // [c][col], 26624 B
    const int n = blockIdx.y, tcb = blockIdx.x;
    const int tid = threadIdx.x;
    const size_t nbase = (size_t)n * (CC * TT * VV);
    const int col0 = tcb * 100;

    for (int l4 = tid; l4 < 1600; l4 += 256) {
        const int c = l4 / 25, q = l4 - c * 25;
        const float4 v = *(const float4*)(x0 + nbase + c * 6400 + col0 + 4 * q);
        *(float4*)&tile[c][4 * q] = v;
    }
    __syncthreads();

    if (tid < 64) {
        float s = 0.f;
        for (int q = 0; q < 25; q++) {
            const float4 v = *(const float4*)&tile[tid][4 * q];
            s += v.x + v.y + v.z + v.w;
        }
        atomicAdd(&pooled[n * 64 + tid], s * (1.f / 6400.f));
    }

    const float* maskg = ws + WS_MASK;
    for (int l = tid; l < 800; l += 256) {
        const int row = l >> 3;                  // 0..99
        const int jb = (l & 7) * 8;
        const int trel = row / 25, i = row - trel * 25;
        const float4 m0 = *(const float4*)(maskg + i * 64 + jb);
        const float4 m1 = *(const float4*)(maskg + i * 64 + jb + 4);
        const float mk[8] = {m0.x, m0.y, m0.z, m0.w, m1.x, m1.y, m1.z, m1.w};
        unsigned outw[4];
#pragma unroll
        for (int pair = 0; pair < 4; pair++) {
            unsigned lo = 0, hi = 0;
#pragma unroll
            for (int hl = 0; hl < 2; hl++) {
                const int j = jb + pair * 2 + hl;
                int jm = j; if (jm >= 50) jm -= 50; else if (jm >= 25) jm -= 25;
                int p = i + jm; if (p >= 25) p -= 25;
                const float v = tile[j][trel * 25 + p] * mk[pair * 2 + hl];
                if (hl == 0) lo = (unsigned)f2bf(v); else hi = (unsigned)f2bf(v);
            }
            outw[pair] = lo | (hi << 16);
        }
        const int grow = col0 + row;
        const int jswz = ((l & 7) ^ (grow & 7)) * 8;     // swizzled 16B granule
        *(uint4*)(xT + ((size_t)(n * 6400) + grow) * 64 + jswz) = *(uint4*)outw;
    }
}

// ---------------- K1: gate MLP + softmax, bfuse ----------------
__global__ __launch_bounds__(256) void k_gate(const float* __restrict__ fc1_w,
                                              const float* __restrict__ fc1_b,
                                              const float* __restrict__ fc2_w,
                                              const float* __restrict__ fc2_b,
                                              const float* __restrict__ lin_b,
                                              const int* __restrict__ epoch_p,
                                              float* ws) {
    const int tid = threadIdx.x;
    float* pooled = ws + WS_POOLED;
    float* gate   = ws + WS_GATE;
    float* bfuse  = ws + WS_BFUSE;

    if (tid < 64) {
        const int n = tid;
        const float* po = pooled + n * 64;
        float h[16];
        for (int q = 0; q < 16; q++) {
            float z = fc1_b[q];
            for (int j = 0; j < 64; j++) z = fmaf(fc1_w[q * 64 + j], po[j], z);
            h[q] = fmaxf(z, 0.f);
        }
        float lg[4];
        for (int k = 0; k < 4; k++) {
            float z = fc2_b[k];
            for (int q = 0; q < 16; q++) z = fmaf(fc2_w[k * 16 + q], h[q], z);
            lg[k] = z;
        }
        const int ep = epoch_p[0];
        const float tao = (ep < 60) ? (-(29.0f / 60.0f) * (float)ep + 30.0f) : 1.0f;
        float mx = -1e30f;
        for (int k = 0; k < 4; k++) { lg[k] /= tao; mx = fmaxf(mx, lg[k]); }
        float se = 0.f;
        for (int k = 0; k < 4; k++) { lg[k] = expf(lg[k] - mx); se += lg[k]; }
        const float inv = 1.f / se;
        for (int k = 0; k < 4; k++) gate[n * 4 + k] = lg[k] * inv;
    }
    __syncthreads();
    for (int f = tid; f < 4096; f += 256) {
        const int n = f >> 6, d = f & 63;
        float s = 0.f;
        for (int k = 0; k < 4; k++) s = fmaf(lin_b[k * 64 + d], gate[n * 4 + k], s);
        bfuse[f] = s;
    }
}

// ---------------- K1b: fused weight, transposed, bf16: Wtb[n][d][c] ----------------
__global__ __launch_bounds__(256) void k_wfuse(const float* __restrict__ lw, float* ws) {
    __shared__ float tile[64 * 65];
    const float* gate = ws + WS_GATE;
    unsigned short* wtb = (unsigned short*)(ws + WS_WTB);
    const int n = blockIdx.x;
    float g[4];
    for (int k = 0; k < 4; k++) g[k] = gate[n * 4 + k];
    for (int f = threadIdx.x; f < 4096; f += 256) {
        const int c = f >> 6, d = f & 63;
        float v = g[0] * lw[f] + g[1] * lw[4096 + f] + g[2] * lw[8192 + f] + g[3] * lw[12288 + f];
        tile[d * 65 + c] = v;
    }
    __syncthreads();
    for (int f = threadIdx.x; f < 4096; f += 256) {
        const int d = f >> 6, c = f & 63;
        wtb[n * 4096 + f] = f2bf(tile[d * 65 + c]);
    }
}

// ---------------- K_gemm: one independent 128-row chunk per block ----------------
// grid (50 tb, 64 n). y[n][tv][d] bf16 direct stores; BN stats via LDS f32 atomics.
__global__ __launch_bounds__(256, 4) void k_gemm(const unsigned short* __restrict__ xT,
                                                 const unsigned short* __restrict__ wtb,
                                                 const float* __restrict__ ws,
                                                 float* __restrict__ wsmut) {
    __shared__ __align__(16) char pool[38800];
    unsigned short (*Wl)[72] = (unsigned short(*)[72])(pool);      // 9216 B
    unsigned short* Xm = (unsigned short*)(pool + 9216);           // [128][64] bf16, 16384 B
    float* s1l = (float*)(pool + 25600);                           // [25][66] 6600 B
    float* s2l = (float*)(pool + 32200);                           // [25][66] 6600 B

    const int n = blockIdx.y, tb = blockIdx.x;
    const int rowbase = tb * 128;                  // ≡ 0 (mod 8): swizzle uses local row bits
    const int tid = threadIdx.x;
    const int wv = tid >> 6, lane = tid & 63;
    const int lrow = lane & 15, lgrp = lane >> 4;
    const int dcol = wv * 16 + lrow;

    // issue chunk DMA first (4 x 16B per thread, exactly 16384 B)
    {
        const char* xc = (const char*)(xT + ((size_t)n * 6400 + rowbase) * 64);
#pragma unroll
        for (int it = 0; it < 4; it++)
            gload_lds16(xc + it * 4096 + tid * 16, (char*)Xm + it * 4096 + tid * 16);
    }
    // stage W + zero stats while DMA flies
    {
        const uint4* wsrc = (const uint4*)(wtb + n * 4096);
#pragma unroll
        for (int it = 0; it < 2; it++) {
            const int itx = tid + it * 256;
            uint4 u = wsrc[itx];
            const int f8 = itx * 8;
            *(uint4*)&Wl[f8 >> 6][f8 & 63] = u;
        }
        for (int f = tid; f < 3300; f += 256) s1l[f] = 0.f;   // covers s1l+s2l (contiguous)
    }
    const float bfv = ws[WS_BFUSE + n * 64 + dcol];
    __syncthreads();          // drains DMA (vmcnt) + W/stat LDS writes (lgkm)

    const bf16x8 w0 = *(const bf16x8*)&Wl[dcol][8 * lgrp];
    const bf16x8 w1 = *(const bf16x8*)&Wl[dcol][32 + 8 * lgrp];

    unsigned short* yg = (unsigned short*)(wsmut + WS_YB) + ((size_t)n * 6400 + rowbase) * 64;
    const int vbase = rowbase % 25;
    const int r7 = lrow & 7;                       // (m*16) ≡ 0 mod 8

#pragma unroll
    for (int m = 0; m < 8; m++) {
        const int rloc = m * 16 + lrow;
        const bf16x8 a0 = *(const bf16x8*)(Xm + rloc * 64 + ((lgrp ^ r7) << 3));
        const bf16x8 a1 = *(const bf16x8*)(Xm + rloc * 64 + (((lgrp + 4) ^ r7) << 3));
        f32x4 a = {bfv, bfv, bfv, bfv};
        a = __builtin_amdgcn_mfma_f32_16x16x32_bf16(a0, w0, a, 0, 0, 0);
        a = __builtin_amdgcn_mfma_f32_16x16x32_bf16(a1, w1, a, 0, 0, 0);
#pragma unroll
        for (int r = 0; r < 4; r++) {
            const int row = m * 16 + 4 * lgrp + r;          // 0..127, all valid
            const unsigned short us = f2bf(a[r]);
            const float yf = bf2f(us);
            int vv = vbase + row;                            // 0..151
            vv -= (vv >= 125) ? 125 : (vv >= 100) ? 100 : (vv >= 75) ? 75 :
                  (vv >= 50) ? 50 : (vv >= 25) ? 25 : 0;
            __hip_atomic_fetch_add(&s1l[vv * 66 + dcol], yf,
                                   __ATOMIC_RELAXED, __HIP_MEMORY_SCOPE_WORKGROUP);
            __hip_atomic_fetch_add(&s2l[vv * 66 + dcol], yf * yf,
                                   __ATOMIC_RELAXED, __HIP_MEMORY_SCOPE_WORKGROUP);
            yg[(size_t)row * 64 + dcol] = us;                // y[n][tv][d]
        }
    }
    __syncthreads();
    // flush stats to hashed global replica (fire-and-forget atomics)
    const int rep = (n * 50 + tb) & (NREP - 1);
    float* g1 = wsmut + WS_S1 + rep * 1600;
    float* g2 = wsmut + WS_S2 + rep * 1600;
    for (int f = tid; f < 1600; f += 256) {
        atomicAdd(&g1[f], s1l[(f >> 6) * 66 + (f & 63)]);
        atomicAdd(&g2[f], s2l[(f >> 6) * 66 + (f & 63)]);
    }
}

// ---------------- K3: finalize BN -> packed bf16 (scale, shift) ----------------
__global__ __launch_bounds__(256) void k_finalize(const float* __restrict__ gamma,
                                                  const float* __restrict__ beta,
                                                  float* ws) {
    const int f = blockIdx.x * 256 + threadIdx.x;   // out-feature v*64+d
    if (f >= VV * DD) return;
    const int v = f >> 6, d = f & 63;
    const int vi = (v - d + 175) % 25;              // source (unshifted) v index
    const int fin = vi * 64 + d;
    float s1 = 0.f, s2 = 0.f;
    for (int rep = 0; rep < NREP; rep++) {
        s1 += ws[WS_S1 + rep * 1600 + fin];
        s2 += ws[WS_S2 + rep * 1600 + fin];
    }
    const float mean = s1 * (1.f / (NN * TT));
    float var = s2 * (1.f / (NN * TT)) - mean * mean;
    var = fmaxf(var, 0.f);
    const float rs = rsqrtf(var + BN_EPS);
    const float a = gamma[f] * rs;
    const float b = beta[f] - mean * a;
    ((unsigned*)ws)[WS_ABP + f] = (unsigned)f2bf(a) | (((unsigned)f2bf(b)) << 16);
}

// ---------------- K_bn: streaming BN + shift-out + residual + relu ----------------
// grid (64 tcb, 64 n): block covers 100 tv-cols x all 64 d of one n.
// y layout [n][tv][d]: stage yL[100][68-pitch] u16; out[n,d,col] = a[vo][d]*y[t*25+vs][d]+b + x0, relu.
__global__ __launch_bounds__(256) void k_bn(const float* __restrict__ x0,
                                            const float* __restrict__ ws,
                                            float* __restrict__ out) {
    __shared__ __align__(16) unsigned short yL[100 * 68];   // 13600 B
    __shared__ unsigned ABl[25 * 68];                       // 6800 B
    const int tcb = blockIdx.x, n = blockIdx.y;
    const int tid = threadIdx.x;
    const int col0 = tcb * 100;
    const unsigned short* yg = (const unsigned short*)(ws + WS_YB) + ((size_t)n * 6400 + col0) * 64;

    // stage y rows (contiguous 12800 B) into pitch-68 LDS (8B granules)
    for (int g = tid; g < 1600; g += 256) {
        const uint2 u = *(const uint2*)(yg + g * 4);
        *(uint2*)&yL[(g >> 4) * 68 + (g & 15) * 4] = u;
    }
    const unsigned* abp = (const unsigned*)(ws + WS_ABP);
    for (int f = tid; f < 1600; f += 256)
        ABl[(f >> 6) * 68 + (f & 63)] = abp[f];
    __syncthreads();

    const size_t pbase = (size_t)n * (CC * TT * VV);
    for (int l4 = tid; l4 < 1600; l4 += 256) {
        const int dd = l4 / 25, q = l4 - dd * 25;
        const int c0 = 4 * q;                      // col within chunk, 0..96
        const float4 xv = *(const float4*)(x0 + pbase + dd * 6400 + col0 + c0);
        const int sh = dd - ((dd >= 50) ? 50 : (dd >= 25) ? 25 : 0);   // d % 25
        float o[4];
        const float xe[4] = {xv.x, xv.y, xv.z, xv.w};
#pragma unroll
        for (int k = 0; k < 4; k++) {
            const int col = c0 + k;
            const int tl = (col >= 75) ? 3 : (col >= 50) ? 2 : (col >= 25) ? 1 : 0;
            const int vo = col - tl * 25;
            int vs = vo - sh; if (vs < 0) vs += 25;
            const unsigned u = ABl[vo * 68 + dd];
            const float a_ = __uint_as_float(u << 16);
            const float b_ = __uint_as_float(u & 0xffff0000u);
            const float y = bf2f(yL[(tl * 25 + vs) * 68 + dd]);
            o[k] = fmaxf(fmaf(a_, y, b_) + xe[k], 0.f);
        }
        float4 ov = {o[0], o[1], o[2], o[3]};
        *(float4*)(out + pbase + dd * 6400 + col0 + c0) = ov;
    }
}

extern "C" void kernel_launch(void* const* d_in, const int* in_sizes, int n_in,
                              void* d_out, int out_size, void* d_ws, size_t ws_size,
                              hipStream_t stream) {
    const float* x0    = (const float*)d_in[0];
    const float* fc1_w = (const float*)d_in[1];
    const float* fc1_b = (const float*)d_in[2];
    const float* fc2_w = (const float*)d_in[3];
    const float* fc2_b = (const float*)d_in[4];
    const float* lw    = (const float*)d_in[5];
    const float* lb    = (const float*)d_in[6];
    const float* fmask = (const float*)d_in[7];
    const float* gamma = (const float*)d_in[8];
    const float* beta  = (const float*)d_in[9];
    const int* epoch   = (const int*)d_in[12];
    float* ws  = (float*)d_ws;
    float* out = (float*)d_out;
    unsigned short* xT = (unsigned short*)d_out;     // lower half of d_out; dead before k_bn writes
    const unsigned short* wtb = (const unsigned short*)(ws + WS_WTB);

    // zero pooled + gate/bfuse/mask/abp + stat replicas
    hipMemsetAsync(d_ws, 0, (size_t)WS_WTB * sizeof(float), stream);

    k_mask<<<7, 256, 0, stream>>>(fmask, ws);
    k_xt<<<dim3(64, 64), 256, 0, stream>>>(x0, ws, ws + WS_POOLED, xT);
    k_gate<<<1, 256, 0, stream>>>(fc1_w, fc1_b, fc2_w, fc2_b, lb, epoch, ws);
    k_wfuse<<<NN, 256, 0, stream>>>(lw, ws);
    k_gemm<<<dim3(50, 64), 256, 0, stream>>>(xT, wtb, ws, ws);
    k_finalize<<<7, 256, 0, stream>>>(gamma, beta, ws);
    k_bn<<<dim3(64, 64), 256, 0, stream>>>(x0, ws, out);
}

// Round 10
// 211.512 us; speedup vs baseline: 1.9490x; 1.9490x over previous
//
#include <hip/hip_runtime.h>
#include <hip/hip_bf16.h>
#include <math.h>

// Shapes
#define NN 64
#define CC 64
#define TT 256
#define VV 25
#define DD 64
#define BN_EPS 1e-5f
#define NREP 16

typedef short bf16x8 __attribute__((ext_vector_type(8)));
typedef float f32x4 __attribute__((ext_vector_type(4)));

// ws layout (float offsets)
#define WS_POOLED 0            // [64][64]  (atomic-accumulated means; memset 0)
#define WS_GATE   4096         // [64][4]
#define WS_BFUSE  4352         // [64][64]
#define WS_MASK   8448         // [25][64] f32
#define WS_ABP    10048        // u32[1600] packed bf16 (a=lo16, b=hi16)
#define WS_S1     13248        // [16][1600] replicas (memset 0)
#define WS_S2     38848        // [16][1600]
#define WS_WTB    64448        // ushort[64][64][64] fused W^T bf16
#define WS_YB     195520       // ushort[64][64][6400] y bf16, layout [n][d][tv]

static __device__ __forceinline__ unsigned short f2bf(float x) {
    __hip_bfloat16 h = __float2bfloat16(x);
    return *(unsigned short*)&h;
}
static __device__ __forceinline__ float bf2f(unsigned short u) {
    return __uint_as_float(((unsigned)u) << 16);
}
// async global->LDS, 16B per lane; dest = wave-uniform base + lane*16 (linear)
static __device__ __forceinline__ void gload_lds16(const void* gsrc, void* ldst) {
    typedef const __attribute__((address_space(1))) unsigned int gu32;
    typedef __attribute__((address_space(3))) unsigned int lu32;
    __builtin_amdgcn_global_load_lds((gu32*)gsrc, (lu32*)ldst, 16, 0, 0);
}

// ---------------- K_mask: mask = tanh(FM)+1 ----------------
__global__ __launch_bounds__(256) void k_mask(const float* __restrict__ fmask, float* ws) {
    const int f = blockIdx.x * 256 + threadIdx.x;
    if (f < VV * CC) ws[WS_MASK + f] = tanhf(fmask[f]) + 1.0f;
}

// ---------------- K_xt: x0 -> xT[n][tv][c] bf16 (shift-in + mask, SWIZZLED), + pooling ----------------
// grid (64 tcb, 64 n). Swizzle: 16B granule g within a 128B row stored at g ^ (grow & 7).
__global__ __launch_bounds__(256) void k_xt(const float* __restrict__ x0,
                                            const float* __restrict__ ws,
                                            float* __restrict__ pooled,
                                            unsigned short* __restrict__ xT) {
    __shared__ __align__(16) float tile[64][104];   // [c][col], 26624 B
    const int n = blockIdx.y, tcb = blockIdx.x;
    const int tid = threadIdx.x;
    const size_t nbase = (size_t)n * (CC * TT * VV);
    const int col0 = tcb * 100;

    for (int l4 = tid; l4 < 1600; l4 += 256) {
        const int c = l4 / 25, q = l4 - c * 25;
        const float4 v = *(const float4*)(x0 + nbase + c * 6400 + col0 + 4 * q);
        *(float4*)&tile[c][4 * q] = v;
    }
    __syncthreads();

    if (tid < 64) {
        float s = 0.f;
        for (int q = 0; q < 25; q++) {
            const float4 v = *(const float4*)&tile[tid][4 * q];
            s += v.x + v.y + v.z + v.w;
        }
        atomicAdd(&pooled[n * 64 + tid], s * (1.f / 6400.f));
    }

    const float* maskg = ws + WS_MASK;
    for (int l = tid; l < 800; l += 256) {
        const int row = l >> 3;                  // 0..99
        const int jb = (l & 7) * 8;
        const int trel = row / 25, i = row - trel * 25;
        const float4 m0 = *(const float4*)(maskg + i * 64 + jb);
        const float4 m1 = *(const float4*)(maskg + i * 64 + jb + 4);
        const float mk[8] = {m0.x, m0.y, m0.z, m0.w, m1.x, m1.y, m1.z, m1.w};
        unsigned outw[4];
#pragma unroll
        for (int pair = 0; pair < 4; pair++) {
            unsigned lo = 0, hi = 0;
#pragma unroll
            for (int hl = 0; hl < 2; hl++) {
                const int j = jb + pair * 2 + hl;
                int jm = j; if (jm >= 50) jm -= 50; else if (jm >= 25) jm -= 25;
                int p = i + jm; if (p >= 25) p -= 25;
                const float v = tile[j][trel * 25 + p] * mk[pair * 2 + hl];
                if (hl == 0) lo = (unsigned)f2bf(v); else hi = (unsigned)f2bf(v);
            }
            outw[pair] = lo | (hi << 16);
        }
        const int grow = col0 + row;
        const int jswz = ((l & 7) ^ (grow & 7)) * 8;     // swizzled 16B granule
        *(uint4*)(xT + ((size_t)(n * 6400) + grow) * 64 + jswz) = *(uint4*)outw;
    }
}

// ---------------- K1: gate MLP + softmax, bfuse ----------------
__global__ __launch_bounds__(256) void k_gate(const float* __restrict__ fc1_w,
                                              const float* __restrict__ fc1_b,
                                              const float* __restrict__ fc2_w,
                                              const float* __restrict__ fc2_b,
                                              const float* __restrict__ lin_b,
                                              const int* __restrict__ epoch_p,
                                              float* ws) {
    const int tid = threadIdx.x;
    float* pooled = ws + WS_POOLED;
    float* gate   = ws + WS_GATE;
    float* bfuse  = ws + WS_BFUSE;

    if (tid < 64) {
        const int n = tid;
        const float* po = pooled + n * 64;
        float h[16];
        for (int q = 0; q < 16; q++) {
            float z = fc1_b[q];
            for (int j = 0; j < 64; j++) z = fmaf(fc1_w[q * 64 + j], po[j], z);
            h[q] = fmaxf(z, 0.f);
        }
        float lg[4];
        for (int k = 0; k < 4; k++) {
            float z = fc2_b[k];
            for (int q = 0; q < 16; q++) z = fmaf(fc2_w[k * 16 + q], h[q], z);
            lg[k] = z;
        }
        const int ep = epoch_p[0];
        const float tao = (ep < 60) ? (-(29.0f / 60.0f) * (float)ep + 30.0f) : 1.0f;
        float mx = -1e30f;
        for (int k = 0; k < 4; k++) { lg[k] /= tao; mx = fmaxf(mx, lg[k]); }
        float se = 0.f;
        for (int k = 0; k < 4; k++) { lg[k] = expf(lg[k] - mx); se += lg[k]; }
        const float inv = 1.f / se;
        for (int k = 0; k < 4; k++) gate[n * 4 + k] = lg[k] * inv;
    }
    __syncthreads();
    for (int f = tid; f < 4096; f += 256) {
        const int n = f >> 6, d = f & 63;
        float s = 0.f;
        for (int k = 0; k < 4; k++) s = fmaf(lin_b[k * 64 + d], gate[n * 4 + k], s);
        bfuse[f] = s;
    }
}

// ---------------- K1b: fused weight, transposed, bf16: Wtb[n][d][c] ----------------
__global__ __launch_bounds__(256) void k_wfuse(const float* __restrict__ lw, float* ws) {
    __shared__ float tile[64 * 65];
    const float* gate = ws + WS_GATE;
    unsigned short* wtb = (unsigned short*)(ws + WS_WTB);
    const int n = blockIdx.x;
    float g[4];
    for (int k = 0; k < 4; k++) g[k] = gate[n * 4 + k];
    for (int f = threadIdx.x; f < 4096; f += 256) {
        const int c = f >> 6, d = f & 63;
        float v = g[0] * lw[f] + g[1] * lw[4096 + f] + g[2] * lw[8192 + f] + g[3] * lw[12288 + f];
        tile[d * 65 + c] = v;
    }
    __syncthreads();
    for (int f = threadIdx.x; f < 4096; f += 256) {
        const int d = f >> 6, c = f & 63;
        wtb[n * 4096 + f] = f2bf(tile[d * 65 + c]);
    }
}

// ---------------- K_gemm: 4-chunk pipeline, dbuf DMA, counted vmcnt, private flush ----------------
// grid (16 tb, 64 n). Per-wave vmcnt event counts are uniform BY CONSTRUCTION:
// prologue: W/bias (3) + DMA0 (4) + DMA1 (4); per chunk: 7 flush stores + (ck<2: 4 DMA).
__global__ __launch_bounds__(256) void k_gemm(const unsigned short* __restrict__ xT,
                                              const unsigned short* __restrict__ wtb,
                                              const float* __restrict__ ws,
                                              float* __restrict__ wsmut) {
    __shared__ __align__(16) char pool[45568];
    // buf0 = pool, buf1 = pool+16384 (128-row Xm chunks, bf16, XOR-swizzled rows)
    // outl = pool+32768: per-wave [16 d][100 rows] bf16 (3200 B each)
    const int n = blockIdx.y, tb = blockIdx.x;
    const int tid = threadIdx.x;
    const int wv = tid >> 6, lane = tid & 63;
    const int lrow = lane & 15, lgrp = lane >> 4;
    const int dcol = wv * 16 + lrow;

    unsigned short* outw = (unsigned short*)(pool + 32768) + wv * 1600;

    // W fragments + bias straight to registers (3 vm events), pinned before DMA
    const bf16x8 w0 = *(const bf16x8*)(wtb + n * 4096 + dcol * 64 + 8 * lgrp);
    const bf16x8 w1 = *(const bf16x8*)(wtb + n * 4096 + dcol * 64 + 32 + 8 * lgrp);
    const float bfv = ws[WS_BFUSE + n * 64 + dcol];
    asm volatile("" ::: "memory");

    const char* xbase = (const char*)(xT + (size_t)n * 6400 * 64);
    {   // DMA chunk0 -> buf0 (4 uniform events/wave)
        const char* src = xbase + (size_t)(tb * 400) * 128;
#pragma unroll
        for (int it = 0; it < 4; it++)
            gload_lds16(src + it * 4096 + tid * 16, pool + it * 4096 + tid * 16);
    }
    asm volatile("" ::: "memory");
    {   // DMA chunk1 -> buf1 (4 events)
        const char* src = xbase + (size_t)(tb * 400 + 100) * 128;
#pragma unroll
        for (int it = 0; it < 4; it++)
            gload_lds16(src + it * 4096 + tid * 16, pool + 16384 + it * 4096 + tid * 16);
    }
    asm volatile("s_waitcnt vmcnt(4)" ::: "memory");   // my chunk0 segs (+W/bias) landed
    asm volatile("s_barrier" ::: "memory");            // => all waves' chunk0 segs landed

    float s1r[7][4], s2r[7][4];
#pragma unroll
    for (int m = 0; m < 7; m++)
#pragma unroll
        for (int r = 0; r < 4; r++) { s1r[m][r] = 0.f; s2r[m][r] = 0.f; }

    unsigned short* yg = (unsigned short*)(wsmut + WS_YB) + (size_t)n * 64 * 6400;

#pragma unroll
    for (int ck = 0; ck < 4; ck++) {
        const int rowt = tb * 400 + ck * 100;
        const unsigned short* Xm = (const unsigned short*)(pool + (ck & 1) * 16384);
        const int b7 = (ck & 1) * 4;                     // = rowt & 7

#pragma unroll
        for (int m = 0; m < 7; m++) {
            const int rloc = m * 16 + lrow;
            const int r7 = (rloc + b7) & 7;
            const bf16x8 a0 = *(const bf16x8*)(Xm + rloc * 64 + ((lgrp ^ r7) << 3));
            const bf16x8 a1 = *(const bf16x8*)(Xm + rloc * 64 + (((lgrp + 4) ^ r7) << 3));
            f32x4 a = {bfv, bfv, bfv, bfv};
            a = __builtin_amdgcn_mfma_f32_16x16x32_bf16(a0, w0, a, 0, 0, 0);
            a = __builtin_amdgcn_mfma_f32_16x16x32_bf16(a1, w1, a, 0, 0, 0);
#pragma unroll
            for (int r = 0; r < 4; r++) {
                const int row = m * 16 + 4 * lgrp + r;
                if (row < 100) {
                    const unsigned short us = f2bf(a[r]);
                    const float yf = bf2f(us);
                    s1r[m][r] += yf;
                    s2r[m][r] = fmaf(yf, yf, s2r[m][r]);
                    outw[lrow * 100 + row] = us;         // private per-wave region
                }
            }
        }
        // flush MY wave's outl (7 uniform store events; no barrier needed)
#pragma unroll
        for (int it = 0; it < 7; it++) {
            const int l = lane + it * 64;
            if (l < 400) {                               // lane-predicate: uniform per wave
                const int dloc = l / 25, q = l - dloc * 25;
                const uint2 u = *(const uint2*)(outw + dloc * 100 + 4 * q);
                *(uint2*)(yg + (size_t)(wv * 16 + dloc) * 6400 + rowt + 4 * q) = u;
            }
        }
        if (ck < 3) {
            // counted: allow my 7 stores in flight; guarantees my next-chunk DMA landed
            asm volatile("s_waitcnt vmcnt(7)" ::: "memory");
            asm volatile("s_barrier" ::: "memory");      // all waves landed + done reading
            if (ck < 2) {                                // DMA chunk ck+2 into freed buffer
                const char* src = xbase + (size_t)(tb * 400 + (ck + 2) * 100) * 128;
                char* dst = pool + (ck & 1) * 16384;
#pragma unroll
                for (int it = 0; it < 4; it++)
                    gload_lds16(src + it * 4096 + tid * 16, dst + it * 4096 + tid * 16);
            }
        }
    }

    // ---- epilogue: stats reduce (LDS region reuse is outside Xm/outl hot path) ----
    __syncthreads();
    float* s1l = (float*)pool;                  // [25][66]
    float* s2l = s1l + 1650;
    for (int f = tid; f < 3300; f += 256) s1l[f] = 0.f;
    __syncthreads();
#pragma unroll
    for (int m = 0; m < 7; m++) {
#pragma unroll
        for (int r = 0; r < 4; r++) {
            const int row = m * 16 + 4 * lgrp + r;
            if (row < 100) {
                int vv = row;
                if (vv >= 75) vv -= 75; else if (vv >= 50) vv -= 50; else if (vv >= 25) vv -= 25;
                __hip_atomic_fetch_add(&s1l[vv * 66 + dcol], s1r[m][r],
                                       __ATOMIC_RELAXED, __HIP_MEMORY_SCOPE_WORKGROUP);
                __hip_atomic_fetch_add(&s2l[vv * 66 + dcol], s2r[m][r],
                                       __ATOMIC_RELAXED, __HIP_MEMORY_SCOPE_WORKGROUP);
            }
        }
    }
    __syncthreads();
    const int rep = (n * 5 + tb) & (NREP - 1);
    float* g1 = wsmut + WS_S1 + rep * 1600;
    float* g2 = wsmut + WS_S2 + rep * 1600;
    for (int f = tid; f < 1600; f += 256) {
        atomicAdd(&g1[f], s1l[(f >> 6) * 66 + (f & 63)]);
        atomicAdd(&g2[f], s2l[(f >> 6) * 66 + (f & 63)]);
    }
}

// ---------------- K3: finalize BN -> packed bf16 (scale, shift) ----------------
__global__ __launch_bounds__(256) void k_finalize(const float* __restrict__ gamma,
                                                  const float* __restrict__ beta,
                                                  float* ws) {
    const int f = blockIdx.x * 256 + threadIdx.x;   // out-feature v*64+d
    if (f >= VV * DD) return;
    const int v = f >> 6, d = f & 63;
    const int vi = (v - d + 175) % 25;              // source (unshifted) v index
    const int fin = vi * 64 + d;
    float s1 = 0.f, s2 = 0.f;
    for (int rep = 0; rep < NREP; rep++) {
        s1 += ws[WS_S1 + rep * 1600 + fin];
        s2 += ws[WS_S2 + rep * 1600 + fin];
    }
    const float mean = s1 * (1.f / (NN * TT));
    float var = s2 * (1.f / (NN * TT)) - mean * mean;
    var = fmaxf(var, 0.f);
    const float rs = rsqrtf(var + BN_EPS);
    const float a = gamma[f] * rs;
    const float b = beta[f] - mean * a;
    ((unsigned*)ws)[WS_ABP + f] = (unsigned)f2bf(a) | (((unsigned)f2bf(b)) << 16);
}

// ---------------- K_bn: streaming BN + shift-out + residual + relu ----------------
// grid (64 d, 64 n): block owns plane (n,d): out[n,d,tv] = a[vo]*y[n,d,t*25+vs]+b[vo]+x0, relu
__global__ __launch_bounds__(256) void k_bn(const float* __restrict__ x0,
                                            const float* __restrict__ ws,
                                            float* __restrict__ out) {
    __shared__ __align__(16) unsigned short ybL[6400];   // 12800 B
    __shared__ float aL[25], bL[25];
    const int d = blockIdx.x, n = blockIdx.y;
    const int tid = threadIdx.x;
    const size_t pbase = (size_t)(n * 64 + d) * 6400;
    const unsigned short* yb = (const unsigned short*)(ws + WS_YB);

    for (int l = tid; l < 800; l += 256)
        *(uint4*)&ybL[l * 8] = *(const uint4*)(yb + pbase + l * 8);
    if (tid < 25) {
        const unsigned u = ((const unsigned*)ws)[WS_ABP + tid * 64 + d];
        aL[tid] = __uint_as_float(u << 16);
        bL[tid] = __uint_as_float(u & 0xffff0000u);
    }
    __syncthreads();

    const int sh = d % 25;
    for (int l4 = tid; l4 < 1600; l4 += 256) {
        const int e0 = 4 * l4;
        const float4 xv = *(const float4*)(x0 + pbase + e0);
        int t = e0 / 25;
        int vo = e0 - 25 * t;
        float o[4];
        const float xe[4] = {xv.x, xv.y, xv.z, xv.w};
#pragma unroll
        for (int k = 0; k < 4; k++) {
            int vs = vo - sh; if (vs < 0) vs += 25;
            const float y = bf2f(ybL[t * 25 + vs]);
            o[k] = fmaxf(fmaf(aL[vo], y, bL[vo]) + xe[k], 0.f);
            vo++; if (vo >= 25) { vo = 0; t++; }
        }
        float4 ov = {o[0], o[1], o[2], o[3]};
        *(float4*)(out + pbase + e0) = ov;
    }
}

extern "C" void kernel_launch(void* const* d_in, const int* in_sizes, int n_in,
                              void* d_out, int out_size, void* d_ws, size_t ws_size,
                              hipStream_t stream) {
    const float* x0    = (const float*)d_in[0];
    const float* fc1_w = (const float*)d_in[1];
    const float* fc1_b = (const float*)d_in[2];
    const float* fc2_w = (const float*)d_in[3];
    const float* fc2_b = (const float*)d_in[4];
    const float* lw    = (const float*)d_in[5];
    const float* lb    = (const float*)d_in[6];
    const float* fmask = (const float*)d_in[7];
    const float* gamma = (const float*)d_in[8];
    const float* beta  = (const float*)d_in[9];
    const int* epoch   = (const int*)d_in[12];
    float* ws  = (float*)d_ws;
    float* out = (float*)d_out;
    unsigned short* xT = (unsigned short*)d_out;     // lower half of d_out; dead before k_bn writes
    const unsigned short* wtb = (const unsigned short*)(ws + WS_WTB);

    // zero pooled + gate/bfuse/mask/abp + stat replicas
    hipMemsetAsync(d_ws, 0, (size_t)WS_WTB * sizeof(float), stream);

    k_mask<<<7, 256, 0, stream>>>(fmask, ws);
    k_xt<<<dim3(64, 64), 256, 0, stream>>>(x0, ws, ws + WS_POOLED, xT);
    k_gate<<<1, 256, 0, stream>>>(fc1_w, fc1_b, fc2_w, fc2_b, lb, epoch, ws);
    k_wfuse<<<NN, 256, 0, stream>>>(lw, ws);
    k_gemm<<<dim3(16, 64), 256, 0, stream>>>(xT, wtb, ws, ws);
    k_finalize<<<7, 256, 0, stream>>>(gamma, beta, ws);
    k_bn<<<dim3(64, 64), 256, 0, stream>>>(x0, ws, out);
}